// Round 6
// baseline (1026.160 us; speedup 1.0000x reference)
//
#include <hip/hip_runtime.h>

#define B_ 64
#define T_ 256
#define DIN_ 1024
#define DOUT_ 1024

// -----------------------------------------------------------------------------
// GEMM: pre[t][o][b] (fp64) = sum_k x[b][t][k] * W[o][k] + bias[o]
// Block = (t0 fixed) x (o-tile 256), all 64 b. Thread (to=tid&15, tb=tid>>4):
//   b = tb*4+i (i<4),  o_local = j4*64 + to*4 + p4  (j = j4*4+p4, j<16).
// fp32 LDS tiles; fragments read as b128 only (1x a, 4x b, all 16B-contiguous
// per 16 lanes => conflict-free). Convert to fp64 in registers; accumulate
// fp64 sequentially over k (bit-identical order to rounds 1/2/5).
// 4x16 per-thread tile: 64 fp64 FMA + 20 cvt per k-step (1.30 overhead ratio).
// -----------------------------------------------------------------------------
__global__ __launch_bounds__(256, 2) void snn_gemm(
    const float* __restrict__ x, const float* __restrict__ W,
    const float* __restrict__ bias, double* __restrict__ pre)
{
    __shared__ float smem[16 * 68 + 16 * 256];   // 4352 + 16384 = 20736 B
    float (*AsF)[68]  = (float(*)[68])smem;              // [k][b]
    float (*BsF)[256] = (float(*)[256])(smem + 16 * 68); // [k][o_local]

    const int t0 = blockIdx.x & 255;
    const int o0 = blockIdx.x >> 8;      // 0..3
    const int tid = threadIdx.x;
    const int to = tid & 15;
    const int tb = tid >> 4;             // 0..15 -> b = tb*4+i

    double acc[4][16];
#pragma unroll
    for (int i = 0; i < 4; ++i)
#pragma unroll
        for (int j = 0; j < 16; ++j) acc[i][j] = 0.0;

    // staging: A = 64 rows(b) x 16 k (4 floats/thread);
    //          B = 256 rows(o) x 16 k (one W row, 16 floats/thread)
    const int arow = tid >> 2;           // b
    const int ak   = (tid & 3) * 4;

    const float* xg = x + (size_t)(t0 + 256 * arow) * DIN_ + ak;
    const float* wg = W + (size_t)(o0 * 256 + tid) * DIN_;

    float4 av  = *(const float4*)(xg);
    float4 bv0 = *(const float4*)(wg);
    float4 bv1 = *(const float4*)(wg + 4);
    float4 bv2 = *(const float4*)(wg + 8);
    float4 bv3 = *(const float4*)(wg + 12);

    for (int kk = 0; kk < DIN_; kk += 16) {
        AsF[ak + 0][arow] = av.x;
        AsF[ak + 1][arow] = av.y;
        AsF[ak + 2][arow] = av.z;
        AsF[ak + 3][arow] = av.w;
        // column write: 64 lanes hit distinct o-columns -> 2 lanes/bank, free
        BsF[ 0][tid] = bv0.x;  BsF[ 1][tid] = bv0.y;
        BsF[ 2][tid] = bv0.z;  BsF[ 3][tid] = bv0.w;
        BsF[ 4][tid] = bv1.x;  BsF[ 5][tid] = bv1.y;
        BsF[ 6][tid] = bv1.z;  BsF[ 7][tid] = bv1.w;
        BsF[ 8][tid] = bv2.x;  BsF[ 9][tid] = bv2.y;
        BsF[10][tid] = bv2.z;  BsF[11][tid] = bv2.w;
        BsF[12][tid] = bv3.x;  BsF[13][tid] = bv3.y;
        BsF[14][tid] = bv3.z;  BsF[15][tid] = bv3.w;
        __syncthreads();

        if (kk + 16 < DIN_) {            // prefetch next tile
            av  = *(const float4*)(xg + kk + 16);
            bv0 = *(const float4*)(wg + kk + 16);
            bv1 = *(const float4*)(wg + kk + 20);
            bv2 = *(const float4*)(wg + kk + 24);
            bv3 = *(const float4*)(wg + kk + 28);
        }

#pragma unroll
        for (int k = 0; k < 16; ++k) {
            const float4 af  = *(const float4*)&AsF[k][tb * 4];
            const float4 bf0 = *(const float4*)&BsF[k][  0 + to * 4];
            const float4 bf1 = *(const float4*)&BsF[k][ 64 + to * 4];
            const float4 bf2 = *(const float4*)&BsF[k][128 + to * 4];
            const float4 bf3 = *(const float4*)&BsF[k][192 + to * 4];
            double a[4], b[16];
            a[0] = (double)af.x;  a[1] = (double)af.y;
            a[2] = (double)af.z;  a[3] = (double)af.w;
            b[ 0] = (double)bf0.x; b[ 1] = (double)bf0.y;
            b[ 2] = (double)bf0.z; b[ 3] = (double)bf0.w;
            b[ 4] = (double)bf1.x; b[ 5] = (double)bf1.y;
            b[ 6] = (double)bf1.z; b[ 7] = (double)bf1.w;
            b[ 8] = (double)bf2.x; b[ 9] = (double)bf2.y;
            b[10] = (double)bf2.z; b[11] = (double)bf2.w;
            b[12] = (double)bf3.x; b[13] = (double)bf3.y;
            b[14] = (double)bf3.z; b[15] = (double)bf3.w;
#pragma unroll
            for (int i = 0; i < 4; ++i)
#pragma unroll
                for (int j = 0; j < 16; ++j)
                    acc[i][j] += a[i] * b[j];   // v_fma_f64
        }
        __syncthreads();
    }

    // epilogue: bias + LDS transpose to b-contiguous stores.
    double biasd[16];
#pragma unroll
    for (int j = 0; j < 16; ++j)
        biasd[j] = (double)bias[o0 * 256 + (j >> 2) * 64 + to * 4 + (j & 3)];

    double (*trans)[67] = (double(*)[67])smem;   // 16 x 67 doubles = 8576 B, fits

    for (int c = 0; c < 16; ++c) {
        __syncthreads();
        // chunk c covers o_local in [c*16, c*16+16): j4 = c>>2, to in [(c&3)*4, +4)
        const int j4  = c >> 2;
        const int tlo = (c & 3) * 4;
        if (to >= tlo && to < tlo + 4) {
#pragma unroll
            for (int p4 = 0; p4 < 4; ++p4) {
                const int r = (to - tlo) * 4 + p4;
                const int j = j4 * 4 + p4;
#pragma unroll
                for (int i = 0; i < 4; ++i)
                    trans[r][tb * 4 + i] = acc[i][j] + biasd[j];
            }
        }
        __syncthreads();
#pragma unroll
        for (int q = 0; q < 4; ++q) {
            const int idx = tid + 256 * q;
            const int b  = idx & 63;
            const int oc = idx >> 6;       // 0..15
            pre[(size_t)(t0 * DOUT_ + o0 * 256 + c * 16 + oc) * 64 + b] = trans[oc][b];
        }
    }
}

// -----------------------------------------------------------------------------
// Scan: one wave per output unit o, lane = b. Batch-mean via ballot+popcount.
// -----------------------------------------------------------------------------
__global__ __launch_bounds__(256) void snn_scan(
    const double* __restrict__ pre, const float* __restrict__ thr_in,
    float* __restrict__ spT, float* __restrict__ outD)
{
    const int wid  = (blockIdx.x * blockDim.x + threadIdx.x) >> 6;
    const int lane = threadIdx.x & 63;
    if (wid >= DOUT_) return;
    const int o = wid;

    double mem = 0.0;
    double thr = (double)thr_in[o];
    const double* p = pre + (size_t)o * 64 + lane;

    for (int t = 0; t < T_; t += 4) {
        double pv[4];
#pragma unroll
        for (int j = 0; j < 4; ++j)
            pv[j] = p[(size_t)(t + j) * (DOUT_ * 64)];
#pragma unroll
        for (int j = 0; j < 4; ++j) {
            mem += pv[j];
            const bool s = (mem >= thr);
            const unsigned long long msk = __ballot(s);
            const int cnt = __popcll(msk);
            thr += 0.05 * ((double)cnt * (1.0 / 64.0) - 0.5);
            const float sf = s ? 1.0f : 0.0f;
            if (spT) {
                spT[(size_t)(t + j) * (DOUT_ * 64) + (size_t)o * 64 + lane] = sf;
            } else {
                outD[(size_t)lane * (T_ * DOUT_) + (size_t)(t + j) * DOUT_ + o] = sf;
            }
            mem = s ? 0.0 : mem;
        }
    }
}

// -----------------------------------------------------------------------------
// Transpose: spT [(t*O+o)][64 b] -> out [64 b][(t*O+o)]
// -----------------------------------------------------------------------------
__global__ __launch_bounds__(256) void snn_transpose(
    const float* __restrict__ spT, float* __restrict__ out)
{
    __shared__ float tile[64][65];
    const int R0   = blockIdx.x * 64;
    const int lane = threadIdx.x & 63;
    const int grp  = threadIdx.x >> 6;
#pragma unroll
    for (int rr = grp; rr < 64; rr += 4)
        tile[rr][lane] = spT[(size_t)(R0 + rr) * 64 + lane];
    __syncthreads();
#pragma unroll
    for (int bq = grp; bq < 64; bq += 4)
        out[(size_t)bq * (T_ * DOUT_) + R0 + lane] = tile[lane][bq];
}

extern "C" void kernel_launch(void* const* d_in, const int* in_sizes, int n_in,
                              void* d_out, int out_size, void* d_ws, size_t ws_size,
                              hipStream_t stream) {
    const float* x    = (const float*)d_in[0];   // [64][256][1024]
    const float* W    = (const float*)d_in[1];   // [1024][1024]
    const float* bias = (const float*)d_in[2];   // [1024]
    const float* thr  = (const float*)d_in[3];   // [1024]
    float* out = (float*)d_out;                  // [64][256][1024]

    double* pre = (double*)d_ws;
    const size_t preBytes = (size_t)T_ * DOUT_ * B_ * sizeof(double);  // 128 MiB
    const size_t spBytes  = (size_t)T_ * DOUT_ * B_ * sizeof(float);   //  64 MiB
    const bool two_stage = (ws_size >= preBytes + spBytes);
    float* spT = two_stage ? (float*)((char*)d_ws + preBytes) : nullptr;

    snn_gemm<<<1024, 256, 0, stream>>>(x, W, bias, pre);
    snn_scan<<<256, 256, 0, stream>>>(pre, thr, spT, two_stage ? nullptr : out);
    if (two_stage)
        snn_transpose<<<4096, 256, 0, stream>>>(spT, out);
}

// Round 7
// 848.109 us; speedup vs baseline: 1.2099x; 1.2099x over previous
//
#include <hip/hip_runtime.h>

#define B_ 64
#define T_ 256
#define DIN_ 1024
#define DOUT_ 1024

// -----------------------------------------------------------------------------
// GEMM: pre[t][o][b] (fp64) = sum_k x[b][t][k] * W[o][k] + bias[o]
// Block = (t0 fixed) x (o-tile 256), all 64 b; grid 1024. BK=8.
// Thread (to=tid&31, tb=tid>>5): b = tb*8+i (i<8),
//   o_local = (j>>2)*128 + to*4 + (j&3)  (j<8).
// fp32 LDS tiles; per k-step: 4x ds_read_b128 (conflict-free), 16 cvt,
// 64 v_fma_f64 (ratio 1.25). fp64 accumulate, sequential k (exactness).
// launch_bounds(256,1): allow full register budget (round 6 spilled at (,2)).
// -----------------------------------------------------------------------------
__global__ __launch_bounds__(256, 1) void snn_gemm(
    const float* __restrict__ x, const float* __restrict__ W,
    const float* __restrict__ bias, double* __restrict__ pre)
{
    __shared__ float smem[8 * 72 + 8 * 256];   // 2304 + 8192 = 10496 B
    float (*AsF)[72]  = (float(*)[72])smem;             // [k][b]
    float (*BsF)[256] = (float(*)[256])(smem + 8 * 72); // [k][o_local]

    const int t0 = blockIdx.x & 255;
    const int o0 = blockIdx.x >> 8;      // 0..3
    const int tid = threadIdx.x;
    const int to = tid & 31;
    const int tb = tid >> 5;             // 0..7 -> b = tb*8+i

    double acc[8][8];
#pragma unroll
    for (int i = 0; i < 8; ++i)
#pragma unroll
        for (int j = 0; j < 8; ++j) acc[i][j] = 0.0;

    // staging: A = 64 b x 8 k (float2/thread); B = 256 o x 8 k (8 floats/thread)
    const int arow = tid >> 2;           // b
    const int ak2  = (tid & 3) * 2;      // k pair

    const float* xg = x + (size_t)(t0 + 256 * arow) * DIN_ + ak2;
    const float* wg = W + (size_t)(o0 * 256 + tid) * DIN_;

    float2 f2  = *(const float2*)(xg);
    float4 bq0 = *(const float4*)(wg);
    float4 bq1 = *(const float4*)(wg + 4);

    for (int kk = 0; kk < DIN_; kk += 8) {
        AsF[ak2 + 0][arow] = f2.x;
        AsF[ak2 + 1][arow] = f2.y;
        BsF[0][tid] = bq0.x;  BsF[1][tid] = bq0.y;
        BsF[2][tid] = bq0.z;  BsF[3][tid] = bq0.w;
        BsF[4][tid] = bq1.x;  BsF[5][tid] = bq1.y;
        BsF[6][tid] = bq1.z;  BsF[7][tid] = bq1.w;
        __syncthreads();

        if (kk + 8 < DIN_) {             // prefetch next tile (10 regs)
            f2  = *(const float2*)(xg + kk + 8);
            bq0 = *(const float4*)(wg + kk + 8);
            bq1 = *(const float4*)(wg + kk + 12);
        }

#pragma unroll
        for (int k = 0; k < 8; ++k) {
            const float4 af0 = *(const float4*)&AsF[k][tb * 8];      // broadcast
            const float4 af1 = *(const float4*)&AsF[k][tb * 8 + 4];
            const float4 bf0 = *(const float4*)&BsF[k][to * 4];      // 512B contig
            const float4 bf1 = *(const float4*)&BsF[k][128 + to * 4];
            double a[8], b[8];
            a[0] = (double)af0.x; a[1] = (double)af0.y;
            a[2] = (double)af0.z; a[3] = (double)af0.w;
            a[4] = (double)af1.x; a[5] = (double)af1.y;
            a[6] = (double)af1.z; a[7] = (double)af1.w;
            b[0] = (double)bf0.x; b[1] = (double)bf0.y;
            b[2] = (double)bf0.z; b[3] = (double)bf0.w;
            b[4] = (double)bf1.x; b[5] = (double)bf1.y;
            b[6] = (double)bf1.z; b[7] = (double)bf1.w;
#pragma unroll
            for (int i = 0; i < 8; ++i)
#pragma unroll
                for (int j = 0; j < 8; ++j)
                    acc[i][j] += a[i] * b[j];   // v_fma_f64
        }
        __syncthreads();
    }

    // epilogue: bias + LDS transpose to b-contiguous stores (16 chunks of 16 o)
    double biasd[8];
#pragma unroll
    for (int j = 0; j < 8; ++j)
        biasd[j] = (double)bias[o0 * 256 + (j >> 2) * 128 + to * 4 + (j & 3)];

    double (*trans)[67] = (double(*)[67])smem;   // 16 x 67 x 8 = 8576 B, fits

    for (int c = 0; c < 16; ++c) {
        __syncthreads();
        const int j4  = c >> 3;          // 0..1
        const int tlo = (c & 7) * 4;
        if (to >= tlo && to < tlo + 4) {
#pragma unroll
            for (int p4 = 0; p4 < 4; ++p4) {
                const int r = (to - tlo) * 4 + p4;   // 0..15
                const int j = j4 * 4 + p4;
#pragma unroll
                for (int i = 0; i < 8; ++i)
                    trans[r][tb * 8 + i] = acc[i][j] + biasd[j];
            }
        }
        __syncthreads();
#pragma unroll
        for (int q = 0; q < 4; ++q) {
            const int idx = tid + 256 * q;
            const int b  = idx & 63;
            const int oc = idx >> 6;       // 0..15
            pre[(size_t)(t0 * DOUT_ + o0 * 256 + c * 16 + oc) * 64 + b] = trans[oc][b];
        }
    }
}

// -----------------------------------------------------------------------------
// Scan: one wave per o, lane = b. Batch-mean via ballot+popcount.
// Emits one 64-bit spike mask per (t,o) (2 MB total) instead of 64 MB floats.
// -----------------------------------------------------------------------------
__global__ __launch_bounds__(256) void snn_scan(
    const double* __restrict__ pre, const float* __restrict__ thr_in,
    unsigned long long* __restrict__ spM, float* __restrict__ outD)
{
    const int wid  = (blockIdx.x * blockDim.x + threadIdx.x) >> 6;
    const int lane = threadIdx.x & 63;
    if (wid >= DOUT_) return;
    const int o = wid;

    double mem = 0.0;
    double thr = (double)thr_in[o];
    const double* p = pre + (size_t)o * 64 + lane;

    for (int t = 0; t < T_; t += 4) {
        double pv[4];
#pragma unroll
        for (int j = 0; j < 4; ++j)
            pv[j] = p[(size_t)(t + j) * (DOUT_ * 64)];
#pragma unroll
        for (int j = 0; j < 4; ++j) {
            mem += pv[j];
            const bool s = (mem >= thr);
            const unsigned long long msk = __ballot(s);
            const int cnt = __popcll(msk);
            thr += 0.05 * ((double)cnt * (1.0 / 64.0) - 0.5);
            if (spM) {
                if (lane == 0) spM[(size_t)(t + j) * DOUT_ + o] = msk;
            } else {
                outD[(size_t)lane * (T_ * DOUT_) + (size_t)(t + j) * DOUT_ + o] =
                    s ? 1.0f : 0.0f;
            }
            mem = s ? 0.0 : mem;
        }
    }
}

// -----------------------------------------------------------------------------
// Expand: spM[t*O+o] bit b -> out[b][t*O+o]. Fully coalesced writes.
// -----------------------------------------------------------------------------
__global__ __launch_bounds__(256) void snn_expand(
    const unsigned long long* __restrict__ spM, float* __restrict__ out)
{
    const int r = blockIdx.x * 256 + threadIdx.x;   // t*DOUT_+o
    const unsigned long long m = spM[r];
#pragma unroll
    for (int b = 0; b < 64; ++b)
        out[(size_t)b * (T_ * DOUT_) + r] = (float)((m >> b) & 1ULL);
}

extern "C" void kernel_launch(void* const* d_in, const int* in_sizes, int n_in,
                              void* d_out, int out_size, void* d_ws, size_t ws_size,
                              hipStream_t stream) {
    const float* x    = (const float*)d_in[0];   // [64][256][1024]
    const float* W    = (const float*)d_in[1];   // [1024][1024]
    const float* bias = (const float*)d_in[2];   // [1024]
    const float* thr  = (const float*)d_in[3];   // [1024]
    float* out = (float*)d_out;                  // [64][256][1024]

    double* pre = (double*)d_ws;
    const size_t preBytes = (size_t)T_ * DOUT_ * B_ * sizeof(double);  // 128 MiB
    const size_t mBytes   = (size_t)T_ * DOUT_ * sizeof(unsigned long long); // 2 MiB
    const bool two_stage = (ws_size >= preBytes + mBytes);
    unsigned long long* spM =
        two_stage ? (unsigned long long*)((char*)d_ws + preBytes) : nullptr;

    snn_gemm<<<1024, 256, 0, stream>>>(x, W, bias, pre);
    snn_scan<<<256, 256, 0, stream>>>(pre, thr, spM, two_stage ? nullptr : out);
    if (two_stage)
        snn_expand<<<1024, 256, 0, stream>>>(spM, out);
}

// Round 8
// 837.815 us; speedup vs baseline: 1.2248x; 1.0123x over previous
//
#include <hip/hip_runtime.h>

#define B_ 64
#define T_ 256
#define DIN_ 1024
#define DOUT_ 1024

// -----------------------------------------------------------------------------
// GEMM: pre[t][o][b] (fp64) = sum_k x[b][t][k] * W[o][k] + bias[o]
// Block = (t0 fixed) x (o-tile 256), all 64 b; grid 1024. BK=8.
// Thread (to=tid&31, tb=tid>>5): b = tb*8+i (i<8),
//   o_local = (j>>2)*128 + to*4 + (j&3)  (j<8).
// fp32 LDS tiles, DOUBLE-buffered (1 barrier per k-chunk); per k-step:
// 4x ds_read_b128 (conflict-free), 16 cvt, 64 v_fma_f64.
// launch_bounds(256,2): acc lives in AGPRs (round-7 evidence), live ~190 regs
// fits 256/wave at 2 waves/SIMD.
// -----------------------------------------------------------------------------
__global__ __launch_bounds__(256, 2) void snn_gemm(
    const float* __restrict__ x, const float* __restrict__ W,
    const float* __restrict__ bias, double* __restrict__ pre)
{
    __shared__ float smem[2][8 * 72 + 8 * 256];   // 2 x 10496 B = 21 KB

    const int t0 = blockIdx.x & 255;
    const int o0 = blockIdx.x >> 8;      // 0..3
    const int tid = threadIdx.x;
    const int to = tid & 31;
    const int tb = tid >> 5;             // 0..7 -> b = tb*8+i

    double acc[8][8];
#pragma unroll
    for (int i = 0; i < 8; ++i)
#pragma unroll
        for (int j = 0; j < 8; ++j) acc[i][j] = 0.0;

    // staging: A = 64 b x 8 k (float2/thread); B = 256 o x 8 k (8 floats/thread)
    const int arow = tid >> 2;           // b
    const int ak2  = (tid & 3) * 2;      // k pair

    const float* xg = x + (size_t)(t0 + 256 * arow) * DIN_ + ak2;
    const float* wg = W + (size_t)(o0 * 256 + tid) * DIN_;

    float2 f2  = *(const float2*)(xg);
    float4 bq0 = *(const float4*)(wg);
    float4 bq1 = *(const float4*)(wg + 4);

    for (int kc = 0; kc < DIN_ / 8; ++kc) {
        float* base = smem[kc & 1];
        float (*AsF)[72]  = (float(*)[72])base;
        float (*BsF)[256] = (float(*)[256])(base + 8 * 72);

        AsF[ak2 + 0][arow] = f2.x;
        AsF[ak2 + 1][arow] = f2.y;
        BsF[0][tid] = bq0.x;  BsF[1][tid] = bq0.y;
        BsF[2][tid] = bq0.z;  BsF[3][tid] = bq0.w;
        BsF[4][tid] = bq1.x;  BsF[5][tid] = bq1.y;
        BsF[6][tid] = bq1.z;  BsF[7][tid] = bq1.w;
        __syncthreads();                 // the ONLY barrier per iteration

        if (kc + 1 < DIN_ / 8) {         // prefetch next tile (10 regs)
            f2  = *(const float2*)(xg + (kc + 1) * 8);
            bq0 = *(const float4*)(wg + (kc + 1) * 8);
            bq1 = *(const float4*)(wg + (kc + 1) * 8 + 4);
        }

#pragma unroll
        for (int k = 0; k < 8; ++k) {
            const float4 af0 = *(const float4*)&AsF[k][tb * 8];      // broadcast
            const float4 af1 = *(const float4*)&AsF[k][tb * 8 + 4];
            const float4 bf0 = *(const float4*)&BsF[k][to * 4];      // 512B contig
            const float4 bf1 = *(const float4*)&BsF[k][128 + to * 4];
            double a[8], b[8];
            a[0] = (double)af0.x; a[1] = (double)af0.y;
            a[2] = (double)af0.z; a[3] = (double)af0.w;
            a[4] = (double)af1.x; a[5] = (double)af1.y;
            a[6] = (double)af1.z; a[7] = (double)af1.w;
            b[0] = (double)bf0.x; b[1] = (double)bf0.y;
            b[2] = (double)bf0.z; b[3] = (double)bf0.w;
            b[4] = (double)bf1.x; b[5] = (double)bf1.y;
            b[6] = (double)bf1.z; b[7] = (double)bf1.w;
#pragma unroll
            for (int i = 0; i < 8; ++i)
#pragma unroll
                for (int j = 0; j < 8; ++j)
                    acc[i][j] += a[i] * b[j];   // v_fma_f64
        }
        // no trailing barrier: next iter writes the OTHER buffer; the next
        // sync orders those writes against this iter's reads interval-safely.
    }

    // epilogue: bias + LDS transpose to b-contiguous stores (16 chunks of 16 o)
    double biasd[8];
#pragma unroll
    for (int j = 0; j < 8; ++j)
        biasd[j] = (double)bias[o0 * 256 + (j >> 2) * 128 + to * 4 + (j & 3)];

    double (*trans)[67] = (double(*)[67])smem[0];   // 16 x 67 x 8 = 8576 B

    for (int c = 0; c < 16; ++c) {
        __syncthreads();
        const int j4  = c >> 3;          // 0..1
        const int tlo = (c & 7) * 4;
        if (to >= tlo && to < tlo + 4) {
#pragma unroll
            for (int p4 = 0; p4 < 4; ++p4) {
                const int r = (to - tlo) * 4 + p4;   // 0..15
                const int j = j4 * 4 + p4;
#pragma unroll
                for (int i = 0; i < 8; ++i)
                    trans[r][tb * 8 + i] = acc[i][j] + biasd[j];
            }
        }
        __syncthreads();
#pragma unroll
        for (int q = 0; q < 4; ++q) {
            const int idx = tid + 256 * q;
            const int b  = idx & 63;
            const int oc = idx >> 6;       // 0..15
            pre[(size_t)(t0 * DOUT_ + o0 * 256 + c * 16 + oc) * 64 + b] = trans[oc][b];
        }
    }
}

// -----------------------------------------------------------------------------
// Scan: one wave per o, lane = b. Batch-mean via ballot+popcount.
// Emits one 64-bit spike mask per (t,o) (2 MB total).
// -----------------------------------------------------------------------------
__global__ __launch_bounds__(256) void snn_scan(
    const double* __restrict__ pre, const float* __restrict__ thr_in,
    unsigned long long* __restrict__ spM, float* __restrict__ outD)
{
    const int wid  = (blockIdx.x * blockDim.x + threadIdx.x) >> 6;
    const int lane = threadIdx.x & 63;
    if (wid >= DOUT_) return;
    const int o = wid;

    double mem = 0.0;
    double thr = (double)thr_in[o];
    const double* p = pre + (size_t)o * 64 + lane;

    for (int t = 0; t < T_; t += 4) {
        double pv[4];
#pragma unroll
        for (int j = 0; j < 4; ++j)
            pv[j] = p[(size_t)(t + j) * (DOUT_ * 64)];
#pragma unroll
        for (int j = 0; j < 4; ++j) {
            mem += pv[j];
            const bool s = (mem >= thr);
            const unsigned long long msk = __ballot(s);
            const int cnt = __popcll(msk);
            thr += 0.05 * ((double)cnt * (1.0 / 64.0) - 0.5);
            if (spM) {
                if (lane == 0) spM[(size_t)(t + j) * DOUT_ + o] = msk;
            } else {
                outD[(size_t)lane * (T_ * DOUT_) + (size_t)(t + j) * DOUT_ + o] =
                    s ? 1.0f : 0.0f;
            }
            mem = s ? 0.0 : mem;
        }
    }
}

// -----------------------------------------------------------------------------
// Expand: spM[t*O+o] bit b -> out[b][t*O+o]. Fully coalesced writes.
// -----------------------------------------------------------------------------
__global__ __launch_bounds__(256) void snn_expand(
    const unsigned long long* __restrict__ spM, float* __restrict__ out)
{
    const int r = blockIdx.x * 256 + threadIdx.x;   // t*DOUT_+o
    const unsigned long long m = spM[r];
#pragma unroll
    for (int b = 0; b < 64; ++b)
        out[(size_t)b * (T_ * DOUT_) + r] = (float)((m >> b) & 1ULL);
}

extern "C" void kernel_launch(void* const* d_in, const int* in_sizes, int n_in,
                              void* d_out, int out_size, void* d_ws, size_t ws_size,
                              hipStream_t stream) {
    const float* x    = (const float*)d_in[0];   // [64][256][1024]
    const float* W    = (const float*)d_in[1];   // [1024][1024]
    const float* bias = (const float*)d_in[2];   // [1024]
    const float* thr  = (const float*)d_in[3];   // [1024]
    float* out = (float*)d_out;                  // [64][256][1024]

    double* pre = (double*)d_ws;
    const size_t preBytes = (size_t)T_ * DOUT_ * B_ * sizeof(double);  // 128 MiB
    const size_t mBytes   = (size_t)T_ * DOUT_ * sizeof(unsigned long long); // 2 MiB
    const bool two_stage = (ws_size >= preBytes + mBytes);
    unsigned long long* spM =
        two_stage ? (unsigned long long*)((char*)d_ws + preBytes) : nullptr;

    snn_gemm<<<1024, 256, 0, stream>>>(x, W, bias, pre);
    snn_scan<<<256, 256, 0, stream>>>(pre, thr, spM, two_stage ? nullptr : out);
    if (two_stage)
        snn_expand<<<1024, 256, 0, stream>>>(spM, out);
}

// Round 9
// 479.678 us; speedup vs baseline: 2.1393x; 1.7466x over previous
//
#include <hip/hip_runtime.h>

#define B_ 64
#define T_ 256
#define DIN_ 1024
#define DOUT_ 1024

typedef int v4i  __attribute__((ext_vector_type(4)));
typedef int v16i __attribute__((ext_vector_type(16)));

#define PRE_BYTES 134217728ULL   // 256*1024*64*8
#define XS_BYTES  100663296ULL   // 6*256*32*2*1024
#define WSL_BYTES 6291456ULL     // 6*32*32*1024
#define SPM_BYTES 2097152ULL     // 256*1024*8

// -----------------------------------------------------------------------------
// Split x into 6 signed-i8 slices, fixed scale 2^3, written in MFMA A-frag
// chunk order: chunk(s,t,kt,mt) = 1KB, byte = lane*16 + j, lane = kh*32+m,
// element = x[b=mt*32+m][t][kt*32+kh*16+j]. All split steps exact in fp32.
// -----------------------------------------------------------------------------
__global__ __launch_bounds__(256) void snn_split_x(
    const float* __restrict__ x, char* __restrict__ xs)
{
    const int W    = blockIdx.x * 4 + (threadIdx.x >> 6);   // 0..16383
    const int lane = threadIdx.x & 63;
    const int mt = W & 1, kt = (W >> 1) & 31, t0 = W >> 6;
    const int m = lane & 31, kh = lane >> 5;
    const int b = mt * 32 + m;

    const float* src = x + ((size_t)b * T_ + t0) * DIN_ + kt * 32 + kh * 16;
    float f[16];
    *(float4*)(f)      = *(const float4*)(src);
    *(float4*)(f + 4)  = *(const float4*)(src + 4);
    *(float4*)(f + 8)  = *(const float4*)(src + 8);
    *(float4*)(f + 12) = *(const float4*)(src + 12);

    unsigned pk[6][4];
#pragma unroll
    for (int s = 0; s < 6; ++s)
        pk[s][0] = pk[s][1] = pk[s][2] = pk[s][3] = 0u;
#pragma unroll
    for (int j = 0; j < 16; ++j) {
        float v = f[j] * 0.125f;                 // / 2^3 (exact)
#pragma unroll
        for (int s = 0; s < 6; ++s) {
            const float ml = (s == 0) ? 64.f : 128.f;
            const float sv = __builtin_rintf(v * ml);
            v = v * ml - sv;                     // exact residual
            const int iv = (int)sv;
            pk[s][j >> 2] |= ((unsigned)iv & 0xffu) << ((j & 3) * 8);
        }
    }
#pragma unroll
    for (int s = 0; s < 6; ++s) {
        char* dst = xs + (size_t)(((s * 256 + t0) * 32 + kt) * 2 + mt) * 1024
                       + lane * 16;
        *(uint4*)dst = make_uint4(pk[s][0], pk[s][1], pk[s][2], pk[s][3]);
    }
}

// -----------------------------------------------------------------------------
// Split W into 6 i8 slices, fixed scale 2^-2, B-frag chunk order:
// chunk(s,ot,kt) = 1KB, element = W[o=ot*32+n][kt*32+kh*16+j].
// -----------------------------------------------------------------------------
__global__ __launch_bounds__(256) void snn_split_w(
    const float* __restrict__ Wt, char* __restrict__ wsl)
{
    const int W    = blockIdx.x * 4 + (threadIdx.x >> 6);   // 0..1023
    const int lane = threadIdx.x & 63;
    const int kt = W & 31, ot = W >> 5;
    const int n = lane & 31, kh = lane >> 5;
    const int o = ot * 32 + n;

    const float* src = Wt + (size_t)o * DIN_ + kt * 32 + kh * 16;
    float f[16];
    *(float4*)(f)      = *(const float4*)(src);
    *(float4*)(f + 4)  = *(const float4*)(src + 4);
    *(float4*)(f + 8)  = *(const float4*)(src + 8);
    *(float4*)(f + 12) = *(const float4*)(src + 12);

    unsigned pk[6][4];
#pragma unroll
    for (int s = 0; s < 6; ++s)
        pk[s][0] = pk[s][1] = pk[s][2] = pk[s][3] = 0u;
#pragma unroll
    for (int j = 0; j < 16; ++j) {
        float v = f[j] * 4.0f;                   // / 2^-2 (exact)
#pragma unroll
        for (int s = 0; s < 6; ++s) {
            const float ml = (s == 0) ? 64.f : 128.f;
            const float sv = __builtin_rintf(v * ml);
            v = v * ml - sv;
            const int iv = (int)sv;
            pk[s][j >> 2] |= ((unsigned)iv & 0xffu) << ((j & 3) * 8);
        }
    }
#pragma unroll
    for (int s = 0; s < 6; ++s) {
        char* dst = wsl + (size_t)((s * 32 + ot) * 32 + kt) * 1024 + lane * 16;
        *(uint4*)dst = make_uint4(pk[s][0], pk[s][1], pk[s][2], pk[s][3]);
    }
}

// -----------------------------------------------------------------------------
// GEMM via i8 MFMA: pre[t][o][b] = 2^-11 * sum_g 2^-7g * S_g + bias.
// Block (t0, oB): 64 b x 64 o; 4 waves = (mt,ot-local) 2x2 of 32x32 tiles.
// 21 slice-pair MFMAs per k-tile (i+j<=5) into 6 i32 acc sets (exact).
// Double-buffered LDS chunks, single barrier per kt (round-8 pattern).
// -----------------------------------------------------------------------------
__global__ __launch_bounds__(256, 2) void snn_gemm_i8(
    const char* __restrict__ xs, const char* __restrict__ wsl,
    const float* __restrict__ bias, double* __restrict__ pre)
{
    __shared__ __align__(16) char lds[2][24 * 1024];
    const int t0 = blockIdx.x & 255;
    const int oB = blockIdx.x >> 8;          // 0..15
    const int tid = threadIdx.x;
    const int w = tid >> 6, lane = tid & 63;
    const int wm = w >> 1, wo = w & 1;

    v16i zero;
#pragma unroll
    for (int r = 0; r < 16; ++r) zero[r] = 0;
    v16i acc[6];
#pragma unroll
    for (int g = 0; g < 6; ++g) acc[g] = zero;

    // each wave stages 6 chunks/kt: waves 0,1 -> A(mt=w), waves 2,3 -> B(ot=w-2)
    const char* src[6];
    int stride, slot0;
    if (w < 2) {
#pragma unroll
        for (int s = 0; s < 6; ++s)
            src[s] = xs + (size_t)(((s * 256 + t0) * 32) * 2 + w) * 1024
                        + lane * 16;
        stride = 2048; slot0 = w * 6;
    } else {
#pragma unroll
        for (int s = 0; s < 6; ++s)
            src[s] = wsl + (size_t)((s * 32 + oB * 2 + (w - 2)) * 32) * 1024
                         + lane * 16;
        stride = 1024; slot0 = 12 + (w - 2) * 6;
    }

    v4i p[6];
#pragma unroll
    for (int s = 0; s < 6; ++s) p[s] = *(const v4i*)(src[s]);

    for (int kt = 0; kt < 32; ++kt) {
        char* buf = lds[kt & 1];
#pragma unroll
        for (int s = 0; s < 6; ++s)
            *(v4i*)(buf + (slot0 + s) * 1024 + lane * 16) = p[s];
        __syncthreads();
        if (kt + 1 < 32) {
#pragma unroll
            for (int s = 0; s < 6; ++s)
                p[s] = *(const v4i*)(src[s] + (size_t)(kt + 1) * stride);
        }
        v4i a[6], b[6];
#pragma unroll
        for (int s = 0; s < 6; ++s) {
            a[s] = *(const v4i*)(buf + (wm * 6 + s) * 1024 + lane * 16);
            b[s] = *(const v4i*)(buf + (12 + wo * 6 + s) * 1024 + lane * 16);
        }
        acc[0] = __builtin_amdgcn_mfma_i32_32x32x32_i8(a[0], b[0], acc[0], 0, 0, 0);
        acc[1] = __builtin_amdgcn_mfma_i32_32x32x32_i8(a[0], b[1], acc[1], 0, 0, 0);
        acc[1] = __builtin_amdgcn_mfma_i32_32x32x32_i8(a[1], b[0], acc[1], 0, 0, 0);
        acc[2] = __builtin_amdgcn_mfma_i32_32x32x32_i8(a[0], b[2], acc[2], 0, 0, 0);
        acc[2] = __builtin_amdgcn_mfma_i32_32x32x32_i8(a[1], b[1], acc[2], 0, 0, 0);
        acc[2] = __builtin_amdgcn_mfma_i32_32x32x32_i8(a[2], b[0], acc[2], 0, 0, 0);
        acc[3] = __builtin_amdgcn_mfma_i32_32x32x32_i8(a[0], b[3], acc[3], 0, 0, 0);
        acc[3] = __builtin_amdgcn_mfma_i32_32x32x32_i8(a[1], b[2], acc[3], 0, 0, 0);
        acc[3] = __builtin_amdgcn_mfma_i32_32x32x32_i8(a[2], b[1], acc[3], 0, 0, 0);
        acc[3] = __builtin_amdgcn_mfma_i32_32x32x32_i8(a[3], b[0], acc[3], 0, 0, 0);
        acc[4] = __builtin_amdgcn_mfma_i32_32x32x32_i8(a[0], b[4], acc[4], 0, 0, 0);
        acc[4] = __builtin_amdgcn_mfma_i32_32x32x32_i8(a[1], b[3], acc[4], 0, 0, 0);
        acc[4] = __builtin_amdgcn_mfma_i32_32x32x32_i8(a[2], b[2], acc[4], 0, 0, 0);
        acc[4] = __builtin_amdgcn_mfma_i32_32x32x32_i8(a[3], b[1], acc[4], 0, 0, 0);
        acc[4] = __builtin_amdgcn_mfma_i32_32x32x32_i8(a[4], b[0], acc[4], 0, 0, 0);
        acc[5] = __builtin_amdgcn_mfma_i32_32x32x32_i8(a[0], b[5], acc[5], 0, 0, 0);
        acc[5] = __builtin_amdgcn_mfma_i32_32x32x32_i8(a[1], b[4], acc[5], 0, 0, 0);
        acc[5] = __builtin_amdgcn_mfma_i32_32x32x32_i8(a[2], b[3], acc[5], 0, 0, 0);
        acc[5] = __builtin_amdgcn_mfma_i32_32x32x32_i8(a[3], b[2], acc[5], 0, 0, 0);
        acc[5] = __builtin_amdgcn_mfma_i32_32x32x32_i8(a[4], b[1], acc[5], 0, 0, 0);
        acc[5] = __builtin_amdgcn_mfma_i32_32x32x32_i8(a[5], b[0], acc[5], 0, 0, 0);
    }

    // epilogue: D layout col=lane&31 (o), row=(r&3)+8*(r>>2)+4*(lane>>5) (b)
    const int n = lane & 31, lh = lane >> 5;
    const int o = oB * 64 + wo * 32 + n;
    const double bv = (double)bias[o];
    double* dst = pre + ((size_t)t0 * DOUT_ + o) * 64 + wm * 32;
#pragma unroll
    for (int r = 0; r < 16; ++r) {
        const int row = (r & 3) + 8 * (r >> 2) + 4 * lh;
        double v = (double)acc[5][r];
        v = v * 0.0078125 + (double)acc[4][r];
        v = v * 0.0078125 + (double)acc[3][r];
        v = v * 0.0078125 + (double)acc[2][r];
        v = v * 0.0078125 + (double)acc[1][r];
        v = v * 0.0078125 + (double)acc[0][r];
        dst[row] = v * 0x1p-11 + bv;             // 2^{3-2-12}
    }
}

// -----------------------------------------------------------------------------
// Fallback GEMM (round-8 proven fp64-VALU path), used when ws is small.
// -----------------------------------------------------------------------------
__global__ __launch_bounds__(256, 2) void snn_gemm_fb(
    const float* __restrict__ x, const float* __restrict__ W,
    const float* __restrict__ bias, double* __restrict__ pre)
{
    __shared__ float smem[2][8 * 72 + 8 * 256];
    const int t0 = blockIdx.x & 255;
    const int o0 = blockIdx.x >> 8;
    const int tid = threadIdx.x;
    const int to = tid & 31;
    const int tb = tid >> 5;

    double acc[8][8];
#pragma unroll
    for (int i = 0; i < 8; ++i)
#pragma unroll
        for (int j = 0; j < 8; ++j) acc[i][j] = 0.0;

    const int arow = tid >> 2;
    const int ak2  = (tid & 3) * 2;
    const float* xg = x + (size_t)(t0 + 256 * arow) * DIN_ + ak2;
    const float* wg = W + (size_t)(o0 * 256 + tid) * DIN_;

    float2 f2  = *(const float2*)(xg);
    float4 bq0 = *(const float4*)(wg);
    float4 bq1 = *(const float4*)(wg + 4);

    for (int kc = 0; kc < DIN_ / 8; ++kc) {
        float* base = smem[kc & 1];
        float (*AsF)[72]  = (float(*)[72])base;
        float (*BsF)[256] = (float(*)[256])(base + 8 * 72);
        AsF[ak2 + 0][arow] = f2.x;
        AsF[ak2 + 1][arow] = f2.y;
        BsF[0][tid] = bq0.x;  BsF[1][tid] = bq0.y;
        BsF[2][tid] = bq0.z;  BsF[3][tid] = bq0.w;
        BsF[4][tid] = bq1.x;  BsF[5][tid] = bq1.y;
        BsF[6][tid] = bq1.z;  BsF[7][tid] = bq1.w;
        __syncthreads();
        if (kc + 1 < DIN_ / 8) {
            f2  = *(const float2*)(xg + (kc + 1) * 8);
            bq0 = *(const float4*)(wg + (kc + 1) * 8);
            bq1 = *(const float4*)(wg + (kc + 1) * 8 + 4);
        }
#pragma unroll
        for (int k = 0; k < 8; ++k) {
            const float4 af0 = *(const float4*)&AsF[k][tb * 8];
            const float4 af1 = *(const float4*)&AsF[k][tb * 8 + 4];
            const float4 bf0 = *(const float4*)&BsF[k][to * 4];
            const float4 bf1 = *(const float4*)&BsF[k][128 + to * 4];
            double a[8], b[8];
            a[0] = (double)af0.x; a[1] = (double)af0.y;
            a[2] = (double)af0.z; a[3] = (double)af0.w;
            a[4] = (double)af1.x; a[5] = (double)af1.y;
            a[6] = (double)af1.z; a[7] = (double)af1.w;
            b[0] = (double)bf0.x; b[1] = (double)bf0.y;
            b[2] = (double)bf0.z; b[3] = (double)bf0.w;
            b[4] = (double)bf1.x; b[5] = (double)bf1.y;
            b[6] = (double)bf1.z; b[7] = (double)bf1.w;
#pragma unroll
            for (int i = 0; i < 8; ++i)
#pragma unroll
                for (int j = 0; j < 8; ++j)
                    acc[i][j] += a[i] * b[j];
        }
    }

    double biasd[8];
#pragma unroll
    for (int j = 0; j < 8; ++j)
        biasd[j] = (double)bias[o0 * 256 + (j >> 2) * 128 + to * 4 + (j & 3)];
    double (*trans)[67] = (double(*)[67])smem[0];
    for (int c = 0; c < 16; ++c) {
        __syncthreads();
        const int j4  = c >> 3;
        const int tlo = (c & 7) * 4;
        if (to >= tlo && to < tlo + 4) {
#pragma unroll
            for (int p4 = 0; p4 < 4; ++p4) {
                const int r = (to - tlo) * 4 + p4;
                const int j = j4 * 4 + p4;
#pragma unroll
                for (int i = 0; i < 8; ++i)
                    trans[r][tb * 8 + i] = acc[i][j] + biasd[j];
            }
        }
        __syncthreads();
#pragma unroll
        for (int q = 0; q < 4; ++q) {
            const int idx = tid + 256 * q;
            const int b  = idx & 63;
            const int oc = idx >> 6;
            pre[(size_t)(t0 * DOUT_ + o0 * 256 + c * 16 + oc) * 64 + b] = trans[oc][b];
        }
    }
}

// -----------------------------------------------------------------------------
// Scan: one wave per o, lane = b. Batch-mean via ballot+popcount.
// -----------------------------------------------------------------------------
__global__ __launch_bounds__(256) void snn_scan(
    const double* __restrict__ pre, const float* __restrict__ thr_in,
    unsigned long long* __restrict__ spM, float* __restrict__ outD)
{
    const int wid  = (blockIdx.x * blockDim.x + threadIdx.x) >> 6;
    const int lane = threadIdx.x & 63;
    if (wid >= DOUT_) return;
    const int o = wid;

    double mem = 0.0;
    double thr = (double)thr_in[o];
    const double* p = pre + (size_t)o * 64 + lane;

    for (int t = 0; t < T_; t += 4) {
        double pv[4];
#pragma unroll
        for (int j = 0; j < 4; ++j)
            pv[j] = p[(size_t)(t + j) * (DOUT_ * 64)];
#pragma unroll
        for (int j = 0; j < 4; ++j) {
            mem += pv[j];
            const bool s = (mem >= thr);
            const unsigned long long msk = __ballot(s);
            const int cnt = __popcll(msk);
            thr += 0.05 * ((double)cnt * (1.0 / 64.0) - 0.5);
            if (spM) {
                if (lane == 0) spM[(size_t)(t + j) * DOUT_ + o] = msk;
            } else {
                outD[(size_t)lane * (T_ * DOUT_) + (size_t)(t + j) * DOUT_ + o] =
                    s ? 1.0f : 0.0f;
            }
            mem = s ? 0.0 : mem;
        }
    }
}

__global__ __launch_bounds__(256) void snn_expand(
    const unsigned long long* __restrict__ spM, float* __restrict__ out)
{
    const int r = blockIdx.x * 256 + threadIdx.x;
    const unsigned long long m = spM[r];
#pragma unroll
    for (int b = 0; b < 64; ++b)
        out[(size_t)b * (T_ * DOUT_) + r] = (float)((m >> b) & 1ULL);
}

extern "C" void kernel_launch(void* const* d_in, const int* in_sizes, int n_in,
                              void* d_out, int out_size, void* d_ws, size_t ws_size,
                              hipStream_t stream) {
    const float* x    = (const float*)d_in[0];   // [64][256][1024]
    const float* W    = (const float*)d_in[1];   // [1024][1024]
    const float* bias = (const float*)d_in[2];   // [1024]
    const float* thr  = (const float*)d_in[3];   // [1024]
    float* out = (float*)d_out;                  // [64][256][1024]

    double* pre = (double*)d_ws;
    const size_t need = PRE_BYTES + XS_BYTES + WSL_BYTES + SPM_BYTES;

    if (ws_size >= need) {
        char* xs  = (char*)d_ws + PRE_BYTES;
        char* wsl = xs + XS_BYTES;
        unsigned long long* spM = (unsigned long long*)(wsl + WSL_BYTES);
        snn_split_x<<<4096, 256, 0, stream>>>(x, xs);
        snn_split_w<<<256, 256, 0, stream>>>(W, wsl);
        snn_gemm_i8<<<4096, 256, 0, stream>>>(xs, wsl, bias, pre);
        snn_scan<<<256, 256, 0, stream>>>(pre, thr, spM, nullptr);
        snn_expand<<<1024, 256, 0, stream>>>(spM, out);
    } else {
        const bool two_stage = (ws_size >= PRE_BYTES + SPM_BYTES);
        unsigned long long* spM =
            two_stage ? (unsigned long long*)((char*)d_ws + PRE_BYTES) : nullptr;
        snn_gemm_fb<<<1024, 256, 0, stream>>>(x, W, bias, pre);
        snn_scan<<<256, 256, 0, stream>>>(pre, thr, spM, two_stage ? nullptr : out);
        if (two_stage)
            snn_expand<<<1024, 256, 0, stream>>>(spM, out);
    }
}